// Round 2
// baseline (13516.389 us; speedup 1.0000x reference)
//
#include <hip/hip_runtime.h>
#include <cstdint>
#include <cstddef>

#define N_NODES 100000
#define N_EDGES 1600000
// n_in = n_out = 32; edge MLP: 96 -> 96 -> 129; out MLPs: 160 -> 32

// ================= fallback (atomic) workspace layout — element offsets =====
#define O_S1   0u         // float [N_NODES*32]  segment sum f1
#define O_M4S  3200000u   // float [N_NODES*32]  segment sum f4
#define O_M2K  6400000u   // uint  [N_NODES*32]  ordered-key max f2 (init 0)
#define O_DEG  9600000u   // uint  [N_NODES]     in-degree (init 0)
#define O_M3K  9700000u   // uint  [N_NODES*32]  ordered-key min f3 (init 0xFFFFFFFF)
#define O_WC   12900000u  // float [96*32]       Wm2[:,1:] @ We[0:128]
#define O_C0   12903072u  // float [32]          bm2[1:]  @ We[0:128]
#define WS_ELEMS 12903104u
#define WS_BYTES ((size_t)WS_ELEMS * 4u)

// ================= fast (CSR gather) workspace layout — element offsets =====
// Atomics on device-scope memory cost ~32B fabric traffic each (measured:
// WRITE_SIZE 6.65e6 KB == 206M atomics * 32B). CSR path replaces 204.8M
// payload atomics with 819MB streaming f-store + gathered reads.
#define O2_DEG   0u          // uint  [N_NODES]      in-degree (init 0)
#define O2_OFF   100000u     // uint  [N_NODES+1]    CSR exclusive offsets
#define O2_CUR   200004u     // uint  [N_NODES]      fill cursors (= offsets copy)
#define O2_EIDX  300004u     // uint  [N_EDGES]      edge ids grouped by dst
#define O2_WC    1900004u    // float [96*32]        Wm2[:,1:] @ We[0:128]
#define O2_C0    1903076u    // float [32]           bm2[1:]  @ We[0:128]
#define O2_F     1903108u    // float [N_EDGES*128]  gated messages f (16B aligned)
#define WS2_ELEMS (1903108u + 204800000u)
#define WS2_BYTES ((size_t)WS2_ELEMS * 4u)

// order-preserving float<->uint key: key monotone increasing with float value.
// min real-float key = key(-inf) = 0x007FFFFF > 0, so init 0 is a safe identity
// for max; 0xFFFFFFFF is a safe identity for min. Decoded only when deg>0.
__device__ __forceinline__ unsigned fkey(float v){
  unsigned b = __float_as_uint(v);
  return (b & 0x80000000u) ? ~b : (b | 0x80000000u);
}
__device__ __forceinline__ float fdec(unsigned u){
  unsigned b = (u & 0x80000000u) ? (u & 0x7fffffffu) : ~u;
  return __uint_as_float(b);
}

// acc[j] += xv * w[j], j unrolled so acc stays in VGPRs; w uniform -> scalar loads
template<int NJ>
__device__ __forceinline__ void accN(float xv, const float* __restrict__ w, float* acc){
  #pragma unroll
  for (int j = 0; j < NJ; j++) acc[j] = fmaf(xv, w[j], acc[j]);
}

// ---- precompute Wc = Wm2[:,1:129] @ We[0:128,:]  and  c0 = bm2[1:129] @ We[0:128,:] ----
__global__ __launch_bounds__(256) void gsmp_make_wc(
    const float* __restrict__ Wm2, const float* __restrict__ bm2,
    const float* __restrict__ We, float* __restrict__ Wc, float* __restrict__ c0)
{
  int t = blockIdx.x * 256 + threadIdx.x;
  if (t < 96 * 32) {
    int k = t >> 5, j = t & 31;
    float s = 0.f;
    for (int i = 0; i < 128; i++) s = fmaf(Wm2[k * 129 + 1 + i], We[i * 32 + j], s);
    Wc[t] = s;
  } else if (t < 96 * 32 + 32) {
    int j = t - 96 * 32;
    float s = 0.f;
    for (int i = 0; i < 128; i++) s = fmaf(bm2[1 + i], We[i * 32 + j], s);
    c0[j] = s;
  }
}

// ============================ CSR build =====================================
__global__ __launch_bounds__(256) void gsmp_hist(
    const int* __restrict__ dst, unsigned* __restrict__ deg)
{
  int e = blockIdx.x * 256 + threadIdx.x;
  if (e < N_EDGES) atomicAdd(&deg[dst[e]], 1u);
}

// single-workgroup exclusive scan of deg -> offsets (+ cursor copy).
// wave shfl scan + 16-wave LDS combine; ~400 barriers total.
__global__ __launch_bounds__(1024) void gsmp_scan(float* __restrict__ wsf)
{
  unsigned* deg = (unsigned*)wsf + O2_DEG;
  unsigned* off = (unsigned*)wsf + O2_OFF;
  unsigned* cur = (unsigned*)wsf + O2_CUR;
  __shared__ unsigned wsum[16];
  __shared__ unsigned carry_s, total_s;
  int t = threadIdx.x;
  int w = t >> 6, lane = t & 63;
  if (t == 0) carry_s = 0u;
  __syncthreads();
  for (int base = 0; base < N_NODES; base += 1024) {
    int n = base + t;
    unsigned v = (n < N_NODES) ? deg[n] : 0u;
    unsigned incl = v;
    #pragma unroll
    for (int o = 1; o < 64; o <<= 1) {
      unsigned u = __shfl_up(incl, o, 64);
      if (lane >= o) incl += u;
    }
    if (lane == 63) wsum[w] = incl;
    __syncthreads();
    if (t < 16) {
      unsigned x = wsum[t], inc = x;
      #pragma unroll
      for (int o = 1; o < 16; o <<= 1) {
        unsigned u = __shfl_up(inc, o, 16);
        if (t >= o) inc += u;
      }
      wsum[t] = inc - x;          // exclusive wave offset
      if (t == 15) total_s = inc; // chunk total
    }
    __syncthreads();
    if (n < N_NODES) {
      unsigned exc = carry_s + wsum[w] + incl - v;
      off[n] = exc;
      cur[n] = exc;
    }
    __syncthreads();
    if (t == 0) carry_s += total_s;
    __syncthreads();
  }
  if (t == 0) off[N_NODES] = carry_s;
}

__global__ __launch_bounds__(256) void gsmp_fill(
    const int* __restrict__ dst, float* __restrict__ wsf)
{
  unsigned* cur  = (unsigned*)wsf + O2_CUR;
  unsigned* eidx = (unsigned*)wsf + O2_EIDX;
  int e = blockIdx.x * 256 + threadIdx.x;
  if (e < N_EDGES) {
    unsigned pos = atomicAdd(&cur[dst[e]], 1u);
    eidx[pos] = (unsigned)e;
  }
}

// ============== fast edge kernel: MLP + gate, f store, fused out_ve =========
// h[96] lives entirely in VGPRs (no LDS): every h read below is at a
// compile-time index (loops fully unrolled). LDS=0 removes the 50KB/block
// occupancy cap (was 3 blk/CU = 6 waves); launch_bounds(128,3) pins regalloc
// at <=168 VGPR -> 3 waves/SIMD = 12 waves/CU.
#define EB 128
__global__ __launch_bounds__(EB, 3) void gsmp_edge_fast(
    const float* __restrict__ in_vc, const float* __restrict__ in_ve,
    const int* __restrict__ src, const int* __restrict__ dst,
    const float* __restrict__ Wm1, const float* __restrict__ bm1,
    const float* __restrict__ Wm2, const float* __restrict__ bm2,
    const float* __restrict__ We, const float* __restrict__ be,
    float* __restrict__ ws, float* __restrict__ out_ve)
{
  int e = blockIdx.x * EB + threadIdx.x;
  bool act = e < N_EDGES;
  int e0 = act ? e : 0;
  int sn = src[e0] * 32;
  int dn = dst[e0] * 32;
  size_t eoff = (size_t)e0 * 32;

  // ---- stage 1: h = relu(concat(vc[src], vc[dst], ve) @ Wm1 + bm1) ----
  float h[96];
  #pragma unroll
  for (int j = 0; j < 96; j++) h[j] = bm1[j];

  const float* base0 = in_vc + sn;
  const float* base1 = in_vc + dn;
  const float* base2 = in_ve + eoff;
  #pragma unroll
  for (int r = 0; r < 3; r++) {
    const float* bp = (r == 0) ? base0 : (r == 1) ? base1 : base2;
    const float4* p4 = (const float4*)bp;
    for (int kc = 0; kc < 8; kc++) {            // rolled: 1 float4 load feeds 384 FMA
      float4 xq = p4[kc];
      const float* w = Wm1 + (r * 32 + kc * 4) * 96;
      accN<96>(xq.x, w + 0 * 96, h);
      accN<96>(xq.y, w + 1 * 96, h);
      accN<96>(xq.z, w + 2 * 96, h);
      accN<96>(xq.w, w + 3 * 96, h);
    }
  }
  #pragma unroll
  for (int j = 0; j < 96; j++) h[j] = fmaxf(h[j], 0.f);

  // ---- gate: y0 = h @ Wm2[:,0] + bm2[0]; gate = sigmoid(y0) ----
  float y0 = bm2[0];
  #pragma unroll
  for (int k = 0; k < 96; k++) y0 = fmaf(h[k], Wm2[k * 129], y0);
  float gate = 1.f / (1.f + __expf(-y0));

  float* fbuf = ws + O2_F;

  // ---- f chunks: f_c = gate * (h @ Wm2[:, 1+32c : 33+32c] + bm2[...]) ; store ----
  for (int c = 0; c < 4; c++) {
    float f[32];
    #pragma unroll
    for (int j = 0; j < 32; j++) f[j] = bm2[1 + c * 32 + j];
    #pragma unroll
    for (int k = 0; k < 96; k++)
      accN<32>(h[k], Wm2 + k * 129 + 1 + c * 32, f);
    #pragma unroll
    for (int j = 0; j < 32; j++) f[j] *= gate;
    if (act) {
      float4* fp = (float4*)(fbuf + (size_t)e * 128 + c * 32);
      #pragma unroll
      for (int jc = 0; jc < 8; jc++) {
        float4 o;
        o.x = f[jc * 4 + 0]; o.y = f[jc * 4 + 1];
        o.z = f[jc * 4 + 2]; o.w = f[jc * 4 + 3];
        fp[jc] = o;
      }
    }
  }

  // ---- out_ve = gate*(h@Wc + c0) + in_ve@We[128:160] + be  (f eliminated via Wc) ----
  const float* Wc = ws + O2_WC;
  const float* c0 = ws + O2_C0;
  float ove[32];
  #pragma unroll
  for (int j = 0; j < 32; j++) ove[j] = 0.f;
  #pragma unroll
  for (int k = 0; k < 96; k++)
    accN<32>(h[k], Wc + k * 32, ove);
  #pragma unroll
  for (int j = 0; j < 32; j++) ove[j] = fmaf(gate, ove[j] + c0[j], be[j]);
  {
    const float4* v4 = (const float4*)base2;
    for (int kc = 0; kc < 8; kc++) {
      float4 vq = v4[kc];
      const float* w = We + (128 + kc * 4) * 32;
      accN<32>(vq.x, w + 0 * 32, ove);
      accN<32>(vq.y, w + 1 * 32, ove);
      accN<32>(vq.z, w + 2 * 32, ove);
      accN<32>(vq.w, w + 3 * 32, ove);
    }
  }
  if (act) {
    float4* op = (float4*)(out_ve + eoff);
    #pragma unroll
    for (int jc = 0; jc < 8; jc++) {
      float4 o;
      o.x = ove[jc * 4 + 0]; o.y = ove[jc * 4 + 1];
      o.z = ove[jc * 4 + 2]; o.w = ove[jc * 4 + 3];
      op[jc] = o;
    }
  }
}

// ======== fast node kernel: CSR gather reductions + node MLP ================
// 32 lanes per node (lane j owns feature j); 8 nodes per 256-thread block.
__global__ __launch_bounds__(256) void gsmp_node_fast(
    const float* __restrict__ in_vc, const float* __restrict__ Wr,
    const float* __restrict__ br, const float* __restrict__ ws,
    float* __restrict__ out_vc)
{
  __shared__ float xs[8][128];
  int g = threadIdx.x >> 5;
  int j = threadIdx.x & 31;
  int n = blockIdx.x * 8 + g;

  const unsigned* off  = (const unsigned*)ws + O2_OFF;
  const unsigned* eidx = (const unsigned*)ws + O2_EIDX;
  const float* fbuf = ws + O2_F;

  unsigned beg = 0, end = 0;
  if (n < N_NODES) { beg = off[n]; end = off[n + 1]; }

  const float INF = __builtin_huge_valf();
  float s1 = 0.f, m4 = 0.f, m2 = -INF, m3 = INF;
  for (unsigned i = beg; i < end; i++) {
    unsigned e = eidx[i];                       // uniform across the 32-lane group
    const float* __restrict__ fb = fbuf + (size_t)e * 128;
    s1 += fb[j];                                // coalesced 128B per group
    m2 = fmaxf(m2, fb[32 + j]);
    m3 = fminf(m3, fb[64 + j]);
    m4 += fb[96 + j];
  }
  bool has = end > beg;
  if (!has) { m2 = 0.f; m3 = 0.f; }
  m4 *= has ? (1.f / (float)(end - beg)) : 1.f;

  xs[g][0 * 32 + j] = s1;
  xs[g][1 * 32 + j] = m2;
  xs[g][2 * 32 + j] = m3;
  xs[g][3 * 32 + j] = m4;
  __syncthreads();
  if (n >= N_NODES) return;

  // out[n][j] = br[j] + sum_k x[k] * Wr[k*32+j]; x broadcast (same-addr reads)
  float acc = br[j];
  const float* vcn = in_vc + (size_t)n * 32;
  #pragma unroll 8
  for (int k = 0; k < 32; k++)  acc = fmaf(vcn[k],   Wr[k * 32 + j],        acc);
  const float* xg = xs[g];
  #pragma unroll 8
  for (int k = 0; k < 128; k++) acc = fmaf(xg[k],    Wr[(32 + k) * 32 + j], acc);
  out_vc[(size_t)n * 32 + j] = acc;
}

// ===================== fallback (atomic-scatter) kernels ====================
__global__ __launch_bounds__(EB) void gsmp_edge_kernel(
    const float* __restrict__ in_vc, const float* __restrict__ in_ve,
    const int* __restrict__ src, const int* __restrict__ dst,
    const float* __restrict__ Wm1, const float* __restrict__ bm1,
    const float* __restrict__ Wm2, const float* __restrict__ bm2,
    const float* __restrict__ We, const float* __restrict__ be,
    float* __restrict__ ws, float* __restrict__ out_ve)
{
  __shared__ float hlds[EB * 100];
  int e = blockIdx.x * EB + threadIdx.x;
  bool act = e < N_EDGES;
  int e0 = act ? e : 0;
  int sn = src[e0] * 32;
  int dn = dst[e0] * 32;
  size_t eoff = (size_t)e0 * 32;

  float h[96];
  #pragma unroll
  for (int j = 0; j < 96; j++) h[j] = bm1[j];

  const float* base0 = in_vc + sn;
  const float* base1 = in_vc + dn;
  const float* base2 = in_ve + eoff;
  #pragma unroll
  for (int r = 0; r < 3; r++) {
    const float* bp = (r == 0) ? base0 : (r == 1) ? base1 : base2;
    const float4* p4 = (const float4*)bp;
    for (int kc = 0; kc < 8; kc++) {
      float4 xq = p4[kc];
      const float* w = Wm1 + (r * 32 + kc * 4) * 96;
      accN<96>(xq.x, w + 0 * 96, h);
      accN<96>(xq.y, w + 1 * 96, h);
      accN<96>(xq.z, w + 2 * 96, h);
      accN<96>(xq.w, w + 3 * 96, h);
    }
  }
  float* myh = hlds + threadIdx.x * 100;
  #pragma unroll
  for (int j = 0; j < 96; j += 4) {
    float4 v;
    v.x = fmaxf(h[j + 0], 0.f); v.y = fmaxf(h[j + 1], 0.f);
    v.z = fmaxf(h[j + 2], 0.f); v.w = fmaxf(h[j + 3], 0.f);
    *(float4*)(myh + j) = v;
  }

  const float4* h4 = (const float4*)myh;
  float y0 = bm2[0];
  for (int kc = 0; kc < 24; kc++) {
    float4 hq = h4[kc];
    int k = kc * 4;
    y0 = fmaf(hq.x, Wm2[(k + 0) * 129], y0);
    y0 = fmaf(hq.y, Wm2[(k + 1) * 129], y0);
    y0 = fmaf(hq.z, Wm2[(k + 2) * 129], y0);
    y0 = fmaf(hq.w, Wm2[(k + 3) * 129], y0);
  }
  float gate = 1.f / (1.f + __expf(-y0));

  float* s1  = ws + O_S1;
  float* m4s = ws + O_M4S;
  unsigned* m2k = (unsigned*)ws + O_M2K;
  unsigned* m3k = (unsigned*)ws + O_M3K;
  unsigned* deg = (unsigned*)ws + O_DEG;

  for (int c = 0; c < 4; c++) {
    float f[32];
    #pragma unroll
    for (int j = 0; j < 32; j++) f[j] = bm2[1 + c * 32 + j];
    for (int kc = 0; kc < 24; kc++) {
      float4 hq = h4[kc];
      const float* w = Wm2 + (kc * 4) * 129 + 1 + c * 32;
      accN<32>(hq.x, w + 0 * 129, f);
      accN<32>(hq.y, w + 1 * 129, f);
      accN<32>(hq.z, w + 2 * 129, f);
      accN<32>(hq.w, w + 3 * 129, f);
    }
    #pragma unroll
    for (int j = 0; j < 32; j++) f[j] *= gate;
    if (act) {
      if (c == 0) {
        #pragma unroll
        for (int j = 0; j < 32; j++) atomicAdd(&s1[dn + j], f[j]);
      } else if (c == 1) {
        #pragma unroll
        for (int j = 0; j < 32; j++) atomicMax(&m2k[dn + j], fkey(f[j]));
      } else if (c == 2) {
        #pragma unroll
        for (int j = 0; j < 32; j++) atomicMin(&m3k[dn + j], fkey(f[j]));
      } else {
        #pragma unroll
        for (int j = 0; j < 32; j++) atomicAdd(&m4s[dn + j], f[j]);
      }
    }
  }
  if (act) atomicAdd(&deg[dn >> 5], 1u);

  const float* Wc = ws + O_WC;
  const float* c0 = ws + O_C0;
  float ove[32];
  #pragma unroll
  for (int j = 0; j < 32; j++) ove[j] = 0.f;
  for (int kc = 0; kc < 24; kc++) {
    float4 hq = h4[kc];
    const float* w = Wc + (kc * 4) * 32;
    accN<32>(hq.x, w + 0 * 32, ove);
    accN<32>(hq.y, w + 1 * 32, ove);
    accN<32>(hq.z, w + 2 * 32, ove);
    accN<32>(hq.w, w + 3 * 32, ove);
  }
  #pragma unroll
  for (int j = 0; j < 32; j++) ove[j] = fmaf(gate, ove[j] + c0[j], be[j]);
  {
    const float4* v4 = (const float4*)base2;
    for (int kc = 0; kc < 8; kc++) {
      float4 vq = v4[kc];
      const float* w = We + (128 + kc * 4) * 32;
      accN<32>(vq.x, w + 0 * 32, ove);
      accN<32>(vq.y, w + 1 * 32, ove);
      accN<32>(vq.z, w + 2 * 32, ove);
      accN<32>(vq.w, w + 3 * 32, ove);
    }
  }
  if (act) {
    float4* op = (float4*)(out_ve + eoff);
    #pragma unroll
    for (int jc = 0; jc < 8; jc++) {
      float4 o;
      o.x = ove[jc * 4 + 0]; o.y = ove[jc * 4 + 1];
      o.z = ove[jc * 4 + 2]; o.w = ove[jc * 4 + 3];
      op[jc] = o;
    }
  }
}

__global__ __launch_bounds__(256) void gsmp_node_kernel(
    const float* __restrict__ in_vc, const float* __restrict__ Wr,
    const float* __restrict__ br, const float* __restrict__ ws,
    float* __restrict__ out_vc)
{
  int n = blockIdx.x * 256 + threadIdx.x;
  if (n >= N_NODES) return;
  const float* s1  = ws + O_S1;
  const float* m4s = ws + O_M4S;
  const unsigned* m2k = (const unsigned*)ws + O_M2K;
  const unsigned* m3k = (const unsigned*)ws + O_M3K;
  const unsigned* deg = (const unsigned*)ws + O_DEG;

  unsigned d = deg[n];
  bool has = d > 0;
  float invd = 1.f / (float)(has ? d : 1u);
  int nb = n * 32;

  float acc[32];
  #pragma unroll
  for (int j = 0; j < 32; j++) acc[j] = br[j];

  for (int k = 0; k < 32; k++) accN<32>(in_vc[nb + k],                 Wr + (0   + k) * 32, acc);
  for (int k = 0; k < 32; k++) accN<32>(s1[nb + k],                    Wr + (32  + k) * 32, acc);
  for (int k = 0; k < 32; k++) accN<32>(has ? fdec(m2k[nb + k]) : 0.f, Wr + (64  + k) * 32, acc);
  for (int k = 0; k < 32; k++) accN<32>(has ? fdec(m3k[nb + k]) : 0.f, Wr + (96  + k) * 32, acc);
  for (int k = 0; k < 32; k++) accN<32>(m4s[nb + k] * invd,            Wr + (128 + k) * 32, acc);

  float4* op = (float4*)(out_vc + (size_t)nb);
  #pragma unroll
  for (int jc = 0; jc < 8; jc++) {
    float4 o;
    o.x = acc[jc * 4 + 0]; o.y = acc[jc * 4 + 1];
    o.z = acc[jc * 4 + 2]; o.w = acc[jc * 4 + 3];
    op[jc] = o;
  }
}

extern "C" void kernel_launch(void* const* d_in, const int* in_sizes, int n_in,
                              void* d_out, int out_size, void* d_ws, size_t ws_size,
                              hipStream_t stream) {
  const float* in_vc = (const float*)d_in[0];
  const float* in_ve = (const float*)d_in[1];
  const int*   src   = (const int*)d_in[2];
  const int*   dst   = (const int*)d_in[3];
  const float* Wm1   = (const float*)d_in[4];
  const float* bm1   = (const float*)d_in[5];
  const float* Wm2   = (const float*)d_in[6];
  const float* bm2   = (const float*)d_in[7];
  const float* Wr    = (const float*)d_in[8];
  const float* br    = (const float*)d_in[9];
  const float* We    = (const float*)d_in[10];
  const float* be    = (const float*)d_in[11];

  float* ws     = (float*)d_ws;
  float* out_vc = (float*)d_out;
  float* out_ve = out_vc + (size_t)N_NODES * 32;

  if (ws_size >= WS2_BYTES) {
    // ---------- fast path: CSR gather, no payload atomics ----------
    hipMemsetAsync(ws + O2_DEG, 0, (size_t)N_NODES * 4, stream);
    gsmp_make_wc<<<13, 256, 0, stream>>>(Wm2, bm2, We, ws + O2_WC, ws + O2_C0);
    gsmp_hist<<<(N_EDGES + 255) / 256, 256, 0, stream>>>(dst, (unsigned*)ws + O2_DEG);
    gsmp_scan<<<1, 1024, 0, stream>>>(ws);
    gsmp_fill<<<(N_EDGES + 255) / 256, 256, 0, stream>>>(dst, ws);
    gsmp_edge_fast<<<N_EDGES / EB, EB, 0, stream>>>(
        in_vc, in_ve, src, dst, Wm1, bm1, Wm2, bm2, We, be, ws, out_ve);
    gsmp_node_fast<<<(N_NODES + 7) / 8, 256, 0, stream>>>(in_vc, Wr, br, ws, out_vc);
  } else if (ws_size >= WS_BYTES) {
    // ---------- fallback: verified atomic-scatter path ----------
    hipMemsetAsync(ws + O_S1, 0, (size_t)(O_M3K - O_S1) * 4, stream);
    hipMemsetAsync(ws + O_M3K, 0xFF, (size_t)(N_NODES * 32) * 4, stream);
    gsmp_make_wc<<<13, 256, 0, stream>>>(Wm2, bm2, We, ws + O_WC, ws + O_C0);
    gsmp_edge_kernel<<<N_EDGES / EB, EB, 0, stream>>>(
        in_vc, in_ve, src, dst, Wm1, bm1, Wm2, bm2, We, be, ws, out_ve);
    gsmp_node_kernel<<<(N_NODES + 255) / 256, 256, 0, stream>>>(
        in_vc, Wr, br, ws, out_vc);
  }
  // else: workspace too small — bail cleanly (shows as absmax failure).
}

// Round 3
// 2937.052 us; speedup vs baseline: 4.6020x; 4.6020x over previous
//
#include <hip/hip_runtime.h>
#include <cstdint>
#include <cstddef>

#define N_NODES 100000
#define N_EDGES 1600000
// n_in = n_out = 32; edge MLP: 96 -> 96 -> 129; out MLPs: 160 -> 32

// ================= fallback (atomic) workspace layout — element offsets =====
#define O_S1   0u         // float [N_NODES*32]  segment sum f1
#define O_M4S  3200000u   // float [N_NODES*32]  segment sum f4
#define O_M2K  6400000u   // uint  [N_NODES*32]  ordered-key max f2 (init 0)
#define O_DEG  9600000u   // uint  [N_NODES]     in-degree (init 0)
#define O_M3K  9700000u   // uint  [N_NODES*32]  ordered-key min f3 (init 0xFFFFFFFF)
#define O_WC   12900000u  // float [96*32]       Wm2[:,1:] @ We[0:128]
#define O_C0   12903072u  // float [32]          bm2[1:]  @ We[0:128]
#define WS_ELEMS 12903104u
#define WS_BYTES ((size_t)WS_ELEMS * 4u)

// ================= fast (CSR gather) workspace layout — element offsets =====
// Atomics on device-scope memory cost ~32B fabric traffic each (measured:
// WRITE_SIZE 6.65e6 KB == 206M atomics * 32B). CSR path replaces 204.8M
// payload atomics with 819MB streaming f-store + gathered reads.
#define O2_DEG   0u          // uint  [N_NODES]      in-degree (init 0)
#define O2_OFF   100000u     // uint  [N_NODES+1]    CSR exclusive offsets
#define O2_CUR   200004u     // uint  [N_NODES]      fill cursors (= offsets copy)
#define O2_EIDX  300004u     // uint  [N_EDGES]      edge ids grouped by dst
#define O2_WC    1900004u    // float [96*32]        Wm2[:,1:] @ We[0:128]
#define O2_C0    1903076u    // float [32]           bm2[1:]  @ We[0:128]
#define O2_F     1903108u    // float [N_EDGES*128]  gated messages f (16B aligned)
#define WS2_ELEMS (1903108u + 204800000u)
#define WS2_BYTES ((size_t)WS2_ELEMS * 4u)

// order-preserving float<->uint key: key monotone increasing with float value.
// min real-float key = key(-inf) = 0x007FFFFF > 0, so init 0 is a safe identity
// for max; 0xFFFFFFFF is a safe identity for min. Decoded only when deg>0.
__device__ __forceinline__ unsigned fkey(float v){
  unsigned b = __float_as_uint(v);
  return (b & 0x80000000u) ? ~b : (b | 0x80000000u);
}
__device__ __forceinline__ float fdec(unsigned u){
  unsigned b = (u & 0x80000000u) ? (u & 0x7fffffffu) : ~u;
  return __uint_as_float(b);
}

// acc[j] += xv * w[j], j unrolled so acc stays in VGPRs; w uniform -> scalar loads
template<int NJ>
__device__ __forceinline__ void accN(float xv, const float* __restrict__ w, float* acc){
  #pragma unroll
  for (int j = 0; j < NJ; j++) acc[j] = fmaf(xv, w[j], acc[j]);
}

// ---- precompute Wc = Wm2[:,1:129] @ We[0:128,:]  and  c0 = bm2[1:129] @ We[0:128,:] ----
__global__ __launch_bounds__(256) void gsmp_make_wc(
    const float* __restrict__ Wm2, const float* __restrict__ bm2,
    const float* __restrict__ We, float* __restrict__ Wc, float* __restrict__ c0)
{
  int t = blockIdx.x * 256 + threadIdx.x;
  if (t < 96 * 32) {
    int k = t >> 5, j = t & 31;
    float s = 0.f;
    for (int i = 0; i < 128; i++) s = fmaf(Wm2[k * 129 + 1 + i], We[i * 32 + j], s);
    Wc[t] = s;
  } else if (t < 96 * 32 + 32) {
    int j = t - 96 * 32;
    float s = 0.f;
    for (int i = 0; i < 128; i++) s = fmaf(bm2[1 + i], We[i * 32 + j], s);
    c0[j] = s;
  }
}

// ============================ CSR build =====================================
__global__ __launch_bounds__(256) void gsmp_hist(
    const int* __restrict__ dst, unsigned* __restrict__ deg)
{
  int e = blockIdx.x * 256 + threadIdx.x;
  if (e < N_EDGES) atomicAdd(&deg[dst[e]], 1u);
}

// single-workgroup exclusive scan of deg -> offsets (+ cursor copy).
// wave shfl scan + 16-wave LDS combine; ~400 barriers total.
__global__ __launch_bounds__(1024) void gsmp_scan(float* __restrict__ wsf)
{
  unsigned* deg = (unsigned*)wsf + O2_DEG;
  unsigned* off = (unsigned*)wsf + O2_OFF;
  unsigned* cur = (unsigned*)wsf + O2_CUR;
  __shared__ unsigned wsum[16];
  __shared__ unsigned carry_s, total_s;
  int t = threadIdx.x;
  int w = t >> 6, lane = t & 63;
  if (t == 0) carry_s = 0u;
  __syncthreads();
  for (int base = 0; base < N_NODES; base += 1024) {
    int n = base + t;
    unsigned v = (n < N_NODES) ? deg[n] : 0u;
    unsigned incl = v;
    #pragma unroll
    for (int o = 1; o < 64; o <<= 1) {
      unsigned u = __shfl_up(incl, o, 64);
      if (lane >= o) incl += u;
    }
    if (lane == 63) wsum[w] = incl;
    __syncthreads();
    if (t < 16) {
      unsigned x = wsum[t], inc = x;
      #pragma unroll
      for (int o = 1; o < 16; o <<= 1) {
        unsigned u = __shfl_up(inc, o, 16);
        if (t >= o) inc += u;
      }
      wsum[t] = inc - x;          // exclusive wave offset
      if (t == 15) total_s = inc; // chunk total
    }
    __syncthreads();
    if (n < N_NODES) {
      unsigned exc = carry_s + wsum[w] + incl - v;
      off[n] = exc;
      cur[n] = exc;
    }
    __syncthreads();
    if (t == 0) carry_s += total_s;
    __syncthreads();
  }
  if (t == 0) off[N_NODES] = carry_s;
}

__global__ __launch_bounds__(256) void gsmp_fill(
    const int* __restrict__ dst, float* __restrict__ wsf)
{
  unsigned* cur  = (unsigned*)wsf + O2_CUR;
  unsigned* eidx = (unsigned*)wsf + O2_EIDX;
  int e = blockIdx.x * 256 + threadIdx.x;
  if (e < N_EDGES) {
    unsigned pos = atomicAdd(&cur[dst[e]], 1u);
    eidx[pos] = (unsigned)e;
  }
}

// ============== fast edge kernel: MLP + gate, f store, fused out_ve =========
// h split across storage classes to fix occupancy without spilling (round-2
// lesson: full h[96] in VGPR + f[32] live -> allocator spills to scratch,
// FETCH_SIZE 19GB). h_lo[56] in VGPRs (all reads compile-time-indexed);
// h_hi[40] in LDS (40 floats/thread = 20480B/block -> 8 blocks/CU vs
// round-1's 3; stride 40 floats -> 2-way bank aliasing on ds_read_b128 =
// free). Stage 1 computes the halves sequentially (x re-read, L1/L2-hot)
// so peak liveness ~ max(40,56)+32+temps ~ 110 VGPR.
#define EB 128
#define HLO 56
#define HHI 40
__global__ __launch_bounds__(EB, 3) void gsmp_edge_fast(
    const float* __restrict__ in_vc, const float* __restrict__ in_ve,
    const int* __restrict__ src, const int* __restrict__ dst,
    const float* __restrict__ Wm1, const float* __restrict__ bm1,
    const float* __restrict__ Wm2, const float* __restrict__ bm2,
    const float* __restrict__ We, const float* __restrict__ be,
    float* __restrict__ ws, float* __restrict__ out_ve)
{
  __shared__ float hlds[EB * HHI];
  int e = blockIdx.x * EB + threadIdx.x;
  bool act = e < N_EDGES;
  int e0 = act ? e : 0;
  int sn = src[e0] * 32;
  int dn = dst[e0] * 32;
  size_t eoff = (size_t)e0 * 32;

  const float* base0 = in_vc + sn;
  const float* base1 = in_vc + dn;
  const float* base2 = in_ve + eoff;
  float* myh = hlds + threadIdx.x * HHI;

  // ---- pass A: h_hi = relu(x @ Wm1[:,56:96] + bm1[56:96]) -> own LDS row ----
  {
    float hh[HHI];
    #pragma unroll
    for (int j = 0; j < HHI; j++) hh[j] = bm1[HLO + j];
    #pragma unroll
    for (int r = 0; r < 3; r++) {
      const float* bp = (r == 0) ? base0 : (r == 1) ? base1 : base2;
      const float4* p4 = (const float4*)bp;
      for (int kc = 0; kc < 8; kc++) {          // rolled: 1 float4 feeds 160 FMA
        float4 xq = p4[kc];
        const float* w = Wm1 + (r * 32 + kc * 4) * 96 + HLO;
        accN<HHI>(xq.x, w + 0 * 96, hh);
        accN<HHI>(xq.y, w + 1 * 96, hh);
        accN<HHI>(xq.z, w + 2 * 96, hh);
        accN<HHI>(xq.w, w + 3 * 96, hh);
      }
    }
    #pragma unroll
    for (int j = 0; j < HHI; j += 4) {
      float4 v;
      v.x = fmaxf(hh[j + 0], 0.f); v.y = fmaxf(hh[j + 1], 0.f);
      v.z = fmaxf(hh[j + 2], 0.f); v.w = fmaxf(hh[j + 3], 0.f);
      *(float4*)(myh + j) = v;
    }
  }
  // no __syncthreads: each thread touches only its own LDS row

  // ---- pass B: h_lo = relu(x @ Wm1[:,0:56] + bm1[0:56]) in VGPRs ----
  float hl[HLO];
  #pragma unroll
  for (int j = 0; j < HLO; j++) hl[j] = bm1[j];
  #pragma unroll
  for (int r = 0; r < 3; r++) {
    const float* bp = (r == 0) ? base0 : (r == 1) ? base1 : base2;
    const float4* p4 = (const float4*)bp;
    for (int kc = 0; kc < 8; kc++) {
      float4 xq = p4[kc];
      const float* w = Wm1 + (r * 32 + kc * 4) * 96;
      accN<HLO>(xq.x, w + 0 * 96, hl);
      accN<HLO>(xq.y, w + 1 * 96, hl);
      accN<HLO>(xq.z, w + 2 * 96, hl);
      accN<HLO>(xq.w, w + 3 * 96, hl);
    }
  }
  #pragma unroll
  for (int j = 0; j < HLO; j++) hl[j] = fmaxf(hl[j], 0.f);

  const float4* h4 = (const float4*)myh;

  // ---- gate: y0 = h @ Wm2[:,0] + bm2[0]; gate = sigmoid(y0) ----
  float y0 = bm2[0];
  #pragma unroll
  for (int k = 0; k < HLO; k++) y0 = fmaf(hl[k], Wm2[k * 129], y0);
  for (int kc = 0; kc < HHI / 4; kc++) {
    float4 hq = h4[kc];
    int k = HLO + kc * 4;
    y0 = fmaf(hq.x, Wm2[(k + 0) * 129], y0);
    y0 = fmaf(hq.y, Wm2[(k + 1) * 129], y0);
    y0 = fmaf(hq.z, Wm2[(k + 2) * 129], y0);
    y0 = fmaf(hq.w, Wm2[(k + 3) * 129], y0);
  }
  float gate = 1.f / (1.f + __expf(-y0));

  float* fbuf = ws + O2_F;

  // ---- f chunks: f_c = gate * (h @ Wm2[:, 1+32c : 33+32c] + bm2[...]) ; store ----
  for (int c = 0; c < 4; c++) {
    float f[32];
    #pragma unroll
    for (int j = 0; j < 32; j++) f[j] = bm2[1 + c * 32 + j];
    #pragma unroll
    for (int k = 0; k < HLO; k++)
      accN<32>(hl[k], Wm2 + k * 129 + 1 + c * 32, f);
    for (int kc = 0; kc < HHI / 4; kc++) {
      float4 hq = h4[kc];
      const float* w = Wm2 + (HLO + kc * 4) * 129 + 1 + c * 32;
      accN<32>(hq.x, w + 0 * 129, f);
      accN<32>(hq.y, w + 1 * 129, f);
      accN<32>(hq.z, w + 2 * 129, f);
      accN<32>(hq.w, w + 3 * 129, f);
    }
    #pragma unroll
    for (int j = 0; j < 32; j++) f[j] *= gate;
    if (act) {
      float4* fp = (float4*)(fbuf + (size_t)e * 128 + c * 32);
      #pragma unroll
      for (int jc = 0; jc < 8; jc++) {
        float4 o;
        o.x = f[jc * 4 + 0]; o.y = f[jc * 4 + 1];
        o.z = f[jc * 4 + 2]; o.w = f[jc * 4 + 3];
        fp[jc] = o;
      }
    }
  }

  // ---- out_ve = gate*(h@Wc + c0) + in_ve@We[128:160] + be  (f eliminated via Wc) ----
  const float* Wc = ws + O2_WC;
  const float* c0 = ws + O2_C0;
  float ove[32];
  #pragma unroll
  for (int j = 0; j < 32; j++) ove[j] = 0.f;
  #pragma unroll
  for (int k = 0; k < HLO; k++)
    accN<32>(hl[k], Wc + k * 32, ove);
  for (int kc = 0; kc < HHI / 4; kc++) {
    float4 hq = h4[kc];
    const float* w = Wc + (HLO + kc * 4) * 32;
    accN<32>(hq.x, w + 0 * 32, ove);
    accN<32>(hq.y, w + 1 * 32, ove);
    accN<32>(hq.z, w + 2 * 32, ove);
    accN<32>(hq.w, w + 3 * 32, ove);
  }
  #pragma unroll
  for (int j = 0; j < 32; j++) ove[j] = fmaf(gate, ove[j] + c0[j], be[j]);
  {
    const float4* v4 = (const float4*)base2;
    for (int kc = 0; kc < 8; kc++) {
      float4 vq = v4[kc];
      const float* w = We + (128 + kc * 4) * 32;
      accN<32>(vq.x, w + 0 * 32, ove);
      accN<32>(vq.y, w + 1 * 32, ove);
      accN<32>(vq.z, w + 2 * 32, ove);
      accN<32>(vq.w, w + 3 * 32, ove);
    }
  }
  if (act) {
    float4* op = (float4*)(out_ve + eoff);
    #pragma unroll
    for (int jc = 0; jc < 8; jc++) {
      float4 o;
      o.x = ove[jc * 4 + 0]; o.y = ove[jc * 4 + 1];
      o.z = ove[jc * 4 + 2]; o.w = ove[jc * 4 + 3];
      op[jc] = o;
    }
  }
}

// ======== fast node kernel: CSR gather reductions + node MLP ================
// 32 lanes per node (lane j owns feature j); 8 nodes per 256-thread block.
__global__ __launch_bounds__(256) void gsmp_node_fast(
    const float* __restrict__ in_vc, const float* __restrict__ Wr,
    const float* __restrict__ br, const float* __restrict__ ws,
    float* __restrict__ out_vc)
{
  __shared__ float xs[8][128];
  int g = threadIdx.x >> 5;
  int j = threadIdx.x & 31;
  int n = blockIdx.x * 8 + g;

  const unsigned* off  = (const unsigned*)ws + O2_OFF;
  const unsigned* eidx = (const unsigned*)ws + O2_EIDX;
  const float* fbuf = ws + O2_F;

  unsigned beg = 0, end = 0;
  if (n < N_NODES) { beg = off[n]; end = off[n + 1]; }

  const float INF = __builtin_huge_valf();
  float s1 = 0.f, m4 = 0.f, m2 = -INF, m3 = INF;
  for (unsigned i = beg; i < end; i++) {
    unsigned e = eidx[i];                       // uniform across the 32-lane group
    const float* __restrict__ fb = fbuf + (size_t)e * 128;
    s1 += fb[j];                                // coalesced 128B per group
    m2 = fmaxf(m2, fb[32 + j]);
    m3 = fminf(m3, fb[64 + j]);
    m4 += fb[96 + j];
  }
  bool has = end > beg;
  if (!has) { m2 = 0.f; m3 = 0.f; }
  m4 *= has ? (1.f / (float)(end - beg)) : 1.f;

  xs[g][0 * 32 + j] = s1;
  xs[g][1 * 32 + j] = m2;
  xs[g][2 * 32 + j] = m3;
  xs[g][3 * 32 + j] = m4;
  __syncthreads();
  if (n >= N_NODES) return;

  // out[n][j] = br[j] + sum_k x[k] * Wr[k*32+j]; x broadcast (same-addr reads)
  float acc = br[j];
  const float* vcn = in_vc + (size_t)n * 32;
  #pragma unroll 8
  for (int k = 0; k < 32; k++)  acc = fmaf(vcn[k],   Wr[k * 32 + j],        acc);
  const float* xg = xs[g];
  #pragma unroll 8
  for (int k = 0; k < 128; k++) acc = fmaf(xg[k],    Wr[(32 + k) * 32 + j], acc);
  out_vc[(size_t)n * 32 + j] = acc;
}

// ===================== fallback (atomic-scatter) kernels ====================
__global__ __launch_bounds__(EB) void gsmp_edge_kernel(
    const float* __restrict__ in_vc, const float* __restrict__ in_ve,
    const int* __restrict__ src, const int* __restrict__ dst,
    const float* __restrict__ Wm1, const float* __restrict__ bm1,
    const float* __restrict__ Wm2, const float* __restrict__ bm2,
    const float* __restrict__ We, const float* __restrict__ be,
    float* __restrict__ ws, float* __restrict__ out_ve)
{
  __shared__ float hlds[EB * 100];
  int e = blockIdx.x * EB + threadIdx.x;
  bool act = e < N_EDGES;
  int e0 = act ? e : 0;
  int sn = src[e0] * 32;
  int dn = dst[e0] * 32;
  size_t eoff = (size_t)e0 * 32;

  float h[96];
  #pragma unroll
  for (int j = 0; j < 96; j++) h[j] = bm1[j];

  const float* base0 = in_vc + sn;
  const float* base1 = in_vc + dn;
  const float* base2 = in_ve + eoff;
  #pragma unroll
  for (int r = 0; r < 3; r++) {
    const float* bp = (r == 0) ? base0 : (r == 1) ? base1 : base2;
    const float4* p4 = (const float4*)bp;
    for (int kc = 0; kc < 8; kc++) {
      float4 xq = p4[kc];
      const float* w = Wm1 + (r * 32 + kc * 4) * 96;
      accN<96>(xq.x, w + 0 * 96, h);
      accN<96>(xq.y, w + 1 * 96, h);
      accN<96>(xq.z, w + 2 * 96, h);
      accN<96>(xq.w, w + 3 * 96, h);
    }
  }
  float* myh = hlds + threadIdx.x * 100;
  #pragma unroll
  for (int j = 0; j < 96; j += 4) {
    float4 v;
    v.x = fmaxf(h[j + 0], 0.f); v.y = fmaxf(h[j + 1], 0.f);
    v.z = fmaxf(h[j + 2], 0.f); v.w = fmaxf(h[j + 3], 0.f);
    *(float4*)(myh + j) = v;
  }

  const float4* h4 = (const float4*)myh;
  float y0 = bm2[0];
  for (int kc = 0; kc < 24; kc++) {
    float4 hq = h4[kc];
    int k = kc * 4;
    y0 = fmaf(hq.x, Wm2[(k + 0) * 129], y0);
    y0 = fmaf(hq.y, Wm2[(k + 1) * 129], y0);
    y0 = fmaf(hq.z, Wm2[(k + 2) * 129], y0);
    y0 = fmaf(hq.w, Wm2[(k + 3) * 129], y0);
  }
  float gate = 1.f / (1.f + __expf(-y0));

  float* s1  = ws + O_S1;
  float* m4s = ws + O_M4S;
  unsigned* m2k = (unsigned*)ws + O_M2K;
  unsigned* m3k = (unsigned*)ws + O_M3K;
  unsigned* deg = (unsigned*)ws + O_DEG;

  for (int c = 0; c < 4; c++) {
    float f[32];
    #pragma unroll
    for (int j = 0; j < 32; j++) f[j] = bm2[1 + c * 32 + j];
    for (int kc = 0; kc < 24; kc++) {
      float4 hq = h4[kc];
      const float* w = Wm2 + (kc * 4) * 129 + 1 + c * 32;
      accN<32>(hq.x, w + 0 * 129, f);
      accN<32>(hq.y, w + 1 * 129, f);
      accN<32>(hq.z, w + 2 * 129, f);
      accN<32>(hq.w, w + 3 * 129, f);
    }
    #pragma unroll
    for (int j = 0; j < 32; j++) f[j] *= gate;
    if (act) {
      if (c == 0) {
        #pragma unroll
        for (int j = 0; j < 32; j++) atomicAdd(&s1[dn + j], f[j]);
      } else if (c == 1) {
        #pragma unroll
        for (int j = 0; j < 32; j++) atomicMax(&m2k[dn + j], fkey(f[j]));
      } else if (c == 2) {
        #pragma unroll
        for (int j = 0; j < 32; j++) atomicMin(&m3k[dn + j], fkey(f[j]));
      } else {
        #pragma unroll
        for (int j = 0; j < 32; j++) atomicAdd(&m4s[dn + j], f[j]);
      }
    }
  }
  if (act) atomicAdd(&deg[dn >> 5], 1u);

  const float* Wc = ws + O_WC;
  const float* c0 = ws + O_C0;
  float ove[32];
  #pragma unroll
  for (int j = 0; j < 32; j++) ove[j] = 0.f;
  for (int kc = 0; kc < 24; kc++) {
    float4 hq = h4[kc];
    const float* w = Wc + (kc * 4) * 32;
    accN<32>(hq.x, w + 0 * 32, ove);
    accN<32>(hq.y, w + 1 * 32, ove);
    accN<32>(hq.z, w + 2 * 32, ove);
    accN<32>(hq.w, w + 3 * 32, ove);
  }
  #pragma unroll
  for (int j = 0; j < 32; j++) ove[j] = fmaf(gate, ove[j] + c0[j], be[j]);
  {
    const float4* v4 = (const float4*)base2;
    for (int kc = 0; kc < 8; kc++) {
      float4 vq = v4[kc];
      const float* w = We + (128 + kc * 4) * 32;
      accN<32>(vq.x, w + 0 * 32, ove);
      accN<32>(vq.y, w + 1 * 32, ove);
      accN<32>(vq.z, w + 2 * 32, ove);
      accN<32>(vq.w, w + 3 * 32, ove);
    }
  }
  if (act) {
    float4* op = (float4*)(out_ve + eoff);
    #pragma unroll
    for (int jc = 0; jc < 8; jc++) {
      float4 o;
      o.x = ove[jc * 4 + 0]; o.y = ove[jc * 4 + 1];
      o.z = ove[jc * 4 + 2]; o.w = ove[jc * 4 + 3];
      op[jc] = o;
    }
  }
}

__global__ __launch_bounds__(256) void gsmp_node_kernel(
    const float* __restrict__ in_vc, const float* __restrict__ Wr,
    const float* __restrict__ br, const float* __restrict__ ws,
    float* __restrict__ out_vc)
{
  int n = blockIdx.x * 256 + threadIdx.x;
  if (n >= N_NODES) return;
  const float* s1  = ws + O_S1;
  const float* m4s = ws + O_M4S;
  const unsigned* m2k = (const unsigned*)ws + O_M2K;
  const unsigned* m3k = (const unsigned*)ws + O_M3K;
  const unsigned* deg = (const unsigned*)ws + O_DEG;

  unsigned d = deg[n];
  bool has = d > 0;
  float invd = 1.f / (float)(has ? d : 1u);
  int nb = n * 32;

  float acc[32];
  #pragma unroll
  for (int j = 0; j < 32; j++) acc[j] = br[j];

  for (int k = 0; k < 32; k++) accN<32>(in_vc[nb + k],                 Wr + (0   + k) * 32, acc);
  for (int k = 0; k < 32; k++) accN<32>(s1[nb + k],                    Wr + (32  + k) * 32, acc);
  for (int k = 0; k < 32; k++) accN<32>(has ? fdec(m2k[nb + k]) : 0.f, Wr + (64  + k) * 32, acc);
  for (int k = 0; k < 32; k++) accN<32>(has ? fdec(m3k[nb + k]) : 0.f, Wr + (96  + k) * 32, acc);
  for (int k = 0; k < 32; k++) accN<32>(m4s[nb + k] * invd,            Wr + (128 + k) * 32, acc);

  float4* op = (float4*)(out_vc + (size_t)nb);
  #pragma unroll
  for (int jc = 0; jc < 8; jc++) {
    float4 o;
    o.x = acc[jc * 4 + 0]; o.y = acc[jc * 4 + 1];
    o.z = acc[jc * 4 + 2]; o.w = acc[jc * 4 + 3];
    op[jc] = o;
  }
}

extern "C" void kernel_launch(void* const* d_in, const int* in_sizes, int n_in,
                              void* d_out, int out_size, void* d_ws, size_t ws_size,
                              hipStream_t stream) {
  const float* in_vc = (const float*)d_in[0];
  const float* in_ve = (const float*)d_in[1];
  const int*   src   = (const int*)d_in[2];
  const int*   dst   = (const int*)d_in[3];
  const float* Wm1   = (const float*)d_in[4];
  const float* bm1   = (const float*)d_in[5];
  const float* Wm2   = (const float*)d_in[6];
  const float* bm2   = (const float*)d_in[7];
  const float* Wr    = (const float*)d_in[8];
  const float* br    = (const float*)d_in[9];
  const float* We    = (const float*)d_in[10];
  const float* be    = (const float*)d_in[11];

  float* ws     = (float*)d_ws;
  float* out_vc = (float*)d_out;
  float* out_ve = out_vc + (size_t)N_NODES * 32;

  if (ws_size >= WS2_BYTES) {
    // ---------- fast path: CSR gather, no payload atomics ----------
    hipMemsetAsync(ws + O2_DEG, 0, (size_t)N_NODES * 4, stream);
    gsmp_make_wc<<<13, 256, 0, stream>>>(Wm2, bm2, We, ws + O2_WC, ws + O2_C0);
    gsmp_hist<<<(N_EDGES + 255) / 256, 256, 0, stream>>>(dst, (unsigned*)ws + O2_DEG);
    gsmp_scan<<<1, 1024, 0, stream>>>(ws);
    gsmp_fill<<<(N_EDGES + 255) / 256, 256, 0, stream>>>(dst, ws);
    gsmp_edge_fast<<<N_EDGES / EB, EB, 0, stream>>>(
        in_vc, in_ve, src, dst, Wm1, bm1, Wm2, bm2, We, be, ws, out_ve);
    gsmp_node_fast<<<(N_NODES + 7) / 8, 256, 0, stream>>>(in_vc, Wr, br, ws, out_vc);
  } else if (ws_size >= WS_BYTES) {
    // ---------- fallback: verified atomic-scatter path ----------
    hipMemsetAsync(ws + O_S1, 0, (size_t)(O_M3K - O_S1) * 4, stream);
    hipMemsetAsync(ws + O_M3K, 0xFF, (size_t)(N_NODES * 32) * 4, stream);
    gsmp_make_wc<<<13, 256, 0, stream>>>(Wm2, bm2, We, ws + O_WC, ws + O_C0);
    gsmp_edge_kernel<<<N_EDGES / EB, EB, 0, stream>>>(
        in_vc, in_ve, src, dst, Wm1, bm1, Wm2, bm2, We, be, ws, out_ve);
    gsmp_node_kernel<<<(N_NODES + 255) / 256, 256, 0, stream>>>(
        in_vc, Wr, br, ws, out_vc);
  }
  // else: workspace too small — bail cleanly (shows as absmax failure).
}